// Round 24
// baseline (345.719 us; speedup 1.0000x reference)
//
#include <hip/hip_runtime.h>
#include <stdint.h>

#define BLK 256

static constexpr float F_EPS = 1e-7f;   // GENConv message eps
static constexpr float F_NEG = 0.01f;   // LeakyReLU slope
static constexpr int   TOPK  = 512;
static constexpr int   PA    = 128;     // pcount/ppack grid
static constexpr int   BSH   = 9;       // bucket = dst >> 9 (512 nodes)
static constexpr int   MAXBUK= 256;     // bucket stride (N/512 <= 256)
static constexpr int   CAP   = 8192;    // LDS segment capacity (entries)

typedef unsigned long long u64;

__device__ __forceinline__ unsigned int ord_f32(float f) {
  unsigned int u = __float_as_uint(f);
  return (u & 0x80000000u) ? ~u : (u | 0x80000000u);
}

// ======== register-blocked GEMM tile: block = [NODES=16*TM nodes] x [COUT] ====
// SCORE: fused TopK scoring — per-node dot with poolw, tanh, 49-bit key,
// scores/keys writeout + per-block histogram flush (kills score_kernel pass).
template<int CIN, int COUT, int TM, bool BN, bool LEAKY, bool STAT, bool SCORE>
__global__ __launch_bounds__(256) void gemm_tile(const float* __restrict__ in,
    const float* __restrict__ W, const float* __restrict__ b,
    const float* __restrict__ scale, const float* __restrict__ shift,
    float* __restrict__ out, double* __restrict__ partial,
    const float* __restrict__ pw, float* __restrict__ scores,
    u64* __restrict__ keys, int* __restrict__ ghist, int n) {
  constexpr int TN = COUT / 16;
  constexpr int NODES = 16 * TM;
  constexpr int KC = (CIN > 64) ? 64 : CIN;
  constexpr int NPAD = NODES + 4;
  __shared__ float xs[KC][NPAD];
  __shared__ float wsh[CIN * COUT];
  __shared__ float sB[COUT];
  __shared__ float sSc[BN ? CIN : 4];
  __shared__ float sSh[BN ? CIN : 4];
  __shared__ float sPW[SCORE ? COUT : 4];
  __shared__ float sacc[SCORE ? NODES : 4];
  __shared__ int hl[SCORE ? 256 : 4];
  __shared__ float snorm_sh;
  for (int i = threadIdx.x; i < CIN * COUT; i += 256) wsh[i] = W[i];
  for (int i = threadIdx.x; i < COUT; i += 256) sB[i] = b[i];
  if constexpr (BN) {
    for (int i = threadIdx.x; i < CIN; i += 256) { sSc[i] = scale[i]; sSh[i] = shift[i]; }
  }
  if constexpr (SCORE) {
    for (int i = threadIdx.x; i < COUT; i += 256) sPW[i] = pw[i];
    if (threadIdx.x < NODES) sacc[threadIdx.x] = 0.f;
    if (threadIdx.x < 256) hl[threadIdx.x] = 0;
  }
  __syncthreads();   // all LDS staged before ANY cross-thread read
  if constexpr (SCORE) {
    if (threadIdx.x == 0) {
      float sq = 0.f;
      for (int i = 0; i < COUT; ++i) sq += sPW[i] * sPW[i];
      snorm_sh = 1.f / sqrtf(sq);
    }
  }
  const int tn = threadIdx.x & 15;
  const int tj = threadIdx.x >> 4;
  const int node0 = blockIdx.x * NODES;

  float acc[TM][TN];
  #pragma unroll
  for (int m = 0; m < TM; ++m)
    #pragma unroll
    for (int j = 0; j < TN; ++j) acc[m][j] = sB[tj * TN + j];

  for (int kc = 0; kc < CIN; kc += KC) {
    __syncthreads();
    constexpr int NL = NODES * (KC / 4);
    for (int i = threadIdx.x; i < NL; i += 256) {
      int nd = i / (KC / 4);
      int kq = i - nd * (KC / 4);
      int gn = node0 + nd;
      const float* p = in + (size_t)(gn < n ? gn : n - 1) * CIN + kc + kq * 4;
      float4 v = *reinterpret_cast<const float4*>(p);
      if constexpr (BN) {
        int kb = kc + kq * 4;
        v.x = fmaxf(v.x * sSc[kb+0] + sSh[kb+0], 0.f);
        v.y = fmaxf(v.y * sSc[kb+1] + sSh[kb+1], 0.f);
        v.z = fmaxf(v.z * sSc[kb+2] + sSh[kb+2], 0.f);
        v.w = fmaxf(v.w * sSc[kb+3] + sSh[kb+3], 0.f);
      }
      xs[kq*4+0][nd] = v.x; xs[kq*4+1][nd] = v.y;
      xs[kq*4+2][nd] = v.z; xs[kq*4+3][nd] = v.w;
    }
    __syncthreads();
    #pragma unroll 16
    for (int k = 0; k < KC; ++k) {
      float xv[TM], wv[TN];
      #pragma unroll
      for (int m = 0; m < TM; ++m) xv[m] = xs[k][tn * TM + m];
      #pragma unroll
      for (int j = 0; j < TN; ++j) wv[j] = wsh[(kc + k) * COUT + tj * TN + j];
      #pragma unroll
      for (int m = 0; m < TM; ++m)
        #pragma unroll
        for (int j = 0; j < TN; ++j)
          acc[m][j] += xv[m] * wv[j];
    }
  }
  #pragma unroll
  for (int m = 0; m < TM; ++m) {
    int gn = node0 + tn * TM + m;
    if (gn < n) {
      float* orow = out + (size_t)gn * COUT + tj * TN;
      #pragma unroll
      for (int j = 0; j < TN; j += 4) {
        float a0 = acc[m][j], a1 = acc[m][j+1], a2 = acc[m][j+2], a3 = acc[m][j+3];
        if constexpr (LEAKY) {
          a0 = a0 > 0.f ? a0 : F_NEG * a0;
          a1 = a1 > 0.f ? a1 : F_NEG * a1;
          a2 = a2 > 0.f ? a2 : F_NEG * a2;
          a3 = a3 > 0.f ? a3 : F_NEG * a3;
        }
        float4 r; r.x = a0; r.y = a1; r.z = a2; r.w = a3;
        *reinterpret_cast<float4*>(orow + j) = r;
      }
    }
  }
  if constexpr (SCORE) {
    #pragma unroll
    for (int m = 0; m < TM; ++m) {
      int gn = node0 + tn * TM + m;
      if (gn < n) {
        float pd = 0.f;
        #pragma unroll
        for (int j = 0; j < TN; ++j) {
          float a = acc[m][j];
          if constexpr (LEAKY) a = a > 0.f ? a : F_NEG * a;
          pd += a * sPW[tj * TN + j];
        }
        atomicAdd(&sacc[tn * TM + m], pd);
      }
    }
    __syncthreads();
    if (threadIdx.x < NODES) {
      int gn = node0 + threadIdx.x;
      if (gn < n) {
        float s = tanhf(sacc[threadIdx.x] * snorm_sh);
        scores[gn] = s;
        u64 key = ((u64)ord_f32(s) << 17) | (u64)(0x1FFFF - gn);
        keys[gn] = key;
        atomicAdd(&hl[(int)(key >> 41)], 1);
      }
    }
    __syncthreads();
    if (threadIdx.x < 256) {
      int v = hl[threadIdx.x];
      if (v) atomicAdd(&ghist[threadIdx.x], v);
    }
  }
  if constexpr (STAT) {
    __shared__ double sStat[2 * COUT];
    double sv[TN], qv[TN];
    #pragma unroll
    for (int j = 0; j < TN; ++j) { sv[j] = 0.0; qv[j] = 0.0; }
    #pragma unroll
    for (int m = 0; m < TM; ++m) {
      bool v = (node0 + tn * TM + m) < n;
      #pragma unroll
      for (int j = 0; j < TN; ++j) {
        double a = v ? (double)acc[m][j] : 0.0;
        sv[j] += a; qv[j] += a * a;
      }
    }
    #pragma unroll
    for (int j = 0; j < TN; ++j) {
      for (int off = 8; off; off >>= 1) {
        sv[j] += __shfl_down(sv[j], off, 16);
        qv[j] += __shfl_down(qv[j], off, 16);
      }
    }
    if (tn == 0) {
      #pragma unroll
      for (int j = 0; j < TN; ++j) {
        sStat[tj * TN + j] = sv[j];
        sStat[COUT + tj * TN + j] = qv[j];
      }
    }
    __syncthreads();
    for (int i = threadIdx.x; i < 2 * COUT; i += 256)
      partial[(size_t)blockIdx.x * (2 * COUT) + i] = sStat[i];
  }
}

// ---- BN finalize for gemm_tile partials ----
template<int COUT>
__global__ __launch_bounds__(256) void bn_fin_ws(const double* __restrict__ partial,
    const float* __restrict__ g, const float* __restrict__ be,
    float* __restrict__ sc, float* __restrict__ sh, int n, int nbx) {
  int j = blockIdx.x;
  int t = threadIdx.x;
  double s = 0, q = 0;
  for (int bdx = t; bdx < nbx; bdx += 256) {
    s += partial[(size_t)bdx * (2 * COUT) + j];
    q += partial[(size_t)bdx * (2 * COUT) + COUT + j];
  }
  for (int off = 32; off; off >>= 1) { s += __shfl_down(s, off); q += __shfl_down(q, off); }
  __shared__ double sw[4][2];
  int lane = t & 63, wid = t >> 6;
  if (lane == 0) { sw[wid][0] = s; sw[wid][1] = q; }
  __syncthreads();
  if (t == 0) {
    s = sw[0][0] + sw[1][0] + sw[2][0] + sw[3][0];
    q = sw[0][1] + sw[1][1] + sw[2][1] + sw[3][1];
    double inv_n = 1.0 / (double)n;
    double mu = s * inv_n;
    double var = q * inv_n - mu * mu;
    double scd = (double)g[j] / sqrt(var + 1e-5);
    sc[j] = (float)scd;
    sh[j] = (float)((double)be[j] - mu * scd);
  }
}

// ------- column-tiled dense (conv1 small layers) -------
template<int CIN, int COUT, int JT, bool STAT = false>
__global__ __launch_bounds__(BLK) void lin_kernel(const float* __restrict__ in,
    const float* __restrict__ W, const float* __restrict__ b,
    float* __restrict__ out, double* __restrict__ partial, int n) {
  __shared__ float sW[CIN * JT];
  __shared__ float sB[JT];
  const int j0 = blockIdx.y * JT;
  for (int i = threadIdx.x; i < CIN * JT; i += BLK) {
    int k = i / JT, jj = i - k * JT;
    sW[i] = W[k * COUT + j0 + jj];
  }
  for (int i = threadIdx.x; i < JT; i += BLK) sB[i] = b[j0 + i];
  __syncthreads();
  int node = blockIdx.x * BLK + threadIdx.x;
  bool valid = node < n;
  if constexpr (!STAT) { if (!valid) return; }
  int rnode = valid ? node : (n - 1);
  float acc[JT];
  #pragma unroll
  for (int jj = 0; jj < JT; ++jj) acc[jj] = sB[jj];
  const float* xrow = in + (size_t)rnode * CIN;
  if constexpr ((CIN & 3) == 0) {
    float x[CIN];
    #pragma unroll
    for (int k4 = 0; k4 < CIN / 4; ++k4) {
      float4 v = *reinterpret_cast<const float4*>(xrow + k4 * 4);
      x[4*k4+0] = v.x; x[4*k4+1] = v.y; x[4*k4+2] = v.z; x[4*k4+3] = v.w;
    }
    #pragma unroll
    for (int k = 0; k < CIN; ++k) {
      #pragma unroll
      for (int jj = 0; jj < JT; ++jj)
        acc[jj] += x[k] * sW[k * JT + jj];
    }
  } else {
    #pragma unroll
    for (int k = 0; k < CIN; ++k) {
      float xv = xrow[k];
      #pragma unroll
      for (int jj = 0; jj < JT; ++jj)
        acc[jj] += xv * sW[k * JT + jj];
    }
  }
  if (valid) {
    float* orow = out + (size_t)node * COUT + j0;
    #pragma unroll
    for (int jj = 0; jj < JT; jj += 4) {
      float4 r; r.x = acc[jj]; r.y = acc[jj+1]; r.z = acc[jj+2]; r.w = acc[jj+3];
      *reinterpret_cast<float4*>(orow + jj) = r;
    }
  }
  if constexpr (STAT) {
    __shared__ double sStat[4][2 * JT];
    int lane = threadIdx.x & 63, wid = threadIdx.x >> 6;
    #pragma unroll
    for (int jj = 0; jj < JT; ++jj) {
      double sv = valid ? (double)acc[jj] : 0.0;
      double qv = sv * sv;
      for (int off = 32; off; off >>= 1) {
        sv += __shfl_down(sv, off);
        qv += __shfl_down(qv, off);
      }
      if (lane == 0) { sStat[wid][jj] = sv; sStat[wid][JT + jj] = qv; }
    }
    __syncthreads();
    if (threadIdx.x < 2 * JT) {
      double v = sStat[0][threadIdx.x] + sStat[1][threadIdx.x]
               + sStat[2][threadIdx.x] + sStat[3][threadIdx.x];
      partial[((size_t)blockIdx.y * gridDim.x + blockIdx.x) * (2 * JT) + threadIdx.x] = v;
    }
  }
}

// ---- BN finalize for lin_kernel partials (conv1 path) ----
template<int COUT, int JT>
__global__ __launch_bounds__(256) void bn_fin3(const double* __restrict__ partial,
    const float* __restrict__ g, const float* __restrict__ be,
    float* __restrict__ sc, float* __restrict__ sh, int n, int nbx) {
  int j = blockIdx.x;
  int t = threadIdx.x;
  int jt = j / JT, jj = j - jt * JT;
  double s = 0, q = 0;
  for (int b = t; b < nbx; b += 256) {
    const double* row = partial + ((size_t)jt * nbx + b) * (2 * JT);
    s += row[jj];
    q += row[JT + jj];
  }
  for (int off = 32; off; off >>= 1) { s += __shfl_down(s, off); q += __shfl_down(q, off); }
  __shared__ double sw[4][2];
  int lane = t & 63, wid = t >> 6;
  if (lane == 0) { sw[wid][0] = s; sw[wid][1] = q; }
  __syncthreads();
  if (t == 0) {
    s = sw[0][0] + sw[1][0] + sw[2][0] + sw[3][0];
    q = sw[0][1] + sw[1][1] + sw[2][1] + sw[3][1];
    double inv_n = 1.0 / (double)n;
    double mu = s * inv_n;
    double var = q * inv_n - mu * mu;
    double scd = (double)g[j] / sqrt(var + 1e-5);
    sc[j] = (float)scd;
    sh[j] = (float)((double)be[j] - mu * scd);
  }
}

// ---- conv1 MLP second half: t=relu(h*sc+sh); out=leaky(t@W+b) ----
template<int CIN, int COUT, int JT>
__global__ __launch_bounds__(BLK) void mlp2_kernel(const float* __restrict__ h,
    const float* __restrict__ scale, const float* __restrict__ shift,
    const float* __restrict__ W, const float* __restrict__ b,
    float* __restrict__ out, int n) {
  __shared__ float sW[CIN * JT];
  __shared__ float sB[JT];
  __shared__ float sSc[CIN];
  __shared__ float sSh[CIN];
  const int j0 = blockIdx.y * JT;
  for (int i = threadIdx.x; i < CIN * JT; i += BLK) {
    int k = i / JT, jj = i - k * JT;
    sW[i] = W[k * COUT + j0 + jj];
  }
  for (int i = threadIdx.x; i < JT; i += BLK) sB[i] = b[j0 + i];
  for (int i = threadIdx.x; i < CIN; i += BLK) { sSc[i] = scale[i]; sSh[i] = shift[i]; }
  __syncthreads();
  int node = blockIdx.x * BLK + threadIdx.x;
  if (node >= n) return;
  float acc[JT];
  #pragma unroll
  for (int jj = 0; jj < JT; ++jj) acc[jj] = sB[jj];
  const float* xrow = h + (size_t)node * CIN;
  float x[CIN];
  #pragma unroll
  for (int k4 = 0; k4 < CIN / 4; ++k4) {
    float4 v = *reinterpret_cast<const float4*>(xrow + k4 * 4);
    x[4*k4+0] = fmaxf(v.x * sSc[4*k4+0] + sSh[4*k4+0], 0.f);
    x[4*k4+1] = fmaxf(v.y * sSc[4*k4+1] + sSh[4*k4+1], 0.f);
    x[4*k4+2] = fmaxf(v.z * sSc[4*k4+2] + sSh[4*k4+2], 0.f);
    x[4*k4+3] = fmaxf(v.w * sSc[4*k4+3] + sSh[4*k4+3], 0.f);
  }
  #pragma unroll
  for (int k = 0; k < CIN; ++k) {
    #pragma unroll
    for (int jj = 0; jj < JT; ++jj)
      acc[jj] += x[k] * sW[k * JT + jj];
  }
  float* orow = out + (size_t)node * COUT + j0;
  #pragma unroll
  for (int jj = 0; jj < JT; jj += 4) {
    float a0 = acc[jj], a1 = acc[jj+1], a2 = acc[jj+2], a3 = acc[jj+3];
    a0 = a0 > 0.f ? a0 : F_NEG * a0;
    a1 = a1 > 0.f ? a1 : F_NEG * a1;
    a2 = a2 > 0.f ? a2 : F_NEG * a2;
    a3 = a3 > 0.f ? a3 : F_NEG * a3;
    float4 r; r.x = a0; r.y = a1; r.z = a2; r.w = a3;
    *reinterpret_cast<float4*>(orow + jj) = r;
  }
}

// ---------------- CSR build (atomic-free, bucket counting sort) ----------------
__global__ __launch_bounds__(BLK) void pcount_kernel(const int* __restrict__ dst,
    int* __restrict__ pcnt, int E, int chunk) {
  __shared__ int cb[MAXBUK];
  for (int i = threadIdx.x; i < MAXBUK; i += BLK) cb[i] = 0;
  __syncthreads();
  int e0 = blockIdx.x * chunk;
  int e1 = min(e0 + chunk, E);
  for (int e = e0 + threadIdx.x; e < e1; e += BLK)
    atomicAdd(&cb[dst[e] >> BSH], 1);
  __syncthreads();
  for (int i = threadIdx.x; i < MAXBUK; i += BLK)
    pcnt[blockIdx.x * MAXBUK + i] = cb[i];
}

__global__ __launch_bounds__(256) void pscan_kernel(const int* __restrict__ pcnt,
    int* __restrict__ poff, int* __restrict__ ptot, int nblk, int nbuk) {
  __shared__ int s[256];
  __shared__ int tot[256];
  int t = threadIdx.x;
  int sum = 0;
  if (t < nbuk) {
    for (int blk = 0; blk < nblk; ++blk) {
      int v = pcnt[blk * MAXBUK + t];
      poff[blk * MAXBUK + t] = sum;
      sum += v;
    }
  }
  tot[t] = (t < nbuk) ? sum : 0;
  s[t] = tot[t];
  __syncthreads();
  for (int off = 1; off < 256; off <<= 1) {
    int add = (t >= off) ? s[t - off] : 0;
    __syncthreads();
    s[t] += add;
    __syncthreads();
  }
  if (t < nbuk) ptot[t] = s[t] - tot[t];   // exclusive base
  if (t == 0) ptot[nbuk] = s[255];
}

__global__ __launch_bounds__(BLK) void ppack_kernel(const int* __restrict__ src,
    const int* __restrict__ dst, const int* __restrict__ poff,
    const int* __restrict__ ptot, int* __restrict__ pairbuf, int E, int chunk) {
  __shared__ int cb[MAXBUK];
  for (int i = threadIdx.x; i < MAXBUK; i += BLK)
    cb[i] = ptot[i] + poff[blockIdx.x * MAXBUK + i];
  __syncthreads();
  int e0 = blockIdx.x * chunk;
  int e1 = min(e0 + chunk, E);
  for (int e = e0 + threadIdx.x; e < e1; e += BLK) {
    int d = dst[e], sv = src[e];
    int b = d >> BSH;
    int pos = atomicAdd(&cb[b], 1);
    pairbuf[pos] = ((d & ((1 << BSH) - 1)) << 17) | sv;
  }
}

__global__ __launch_bounds__(BLK) void place_kernel(const int* __restrict__ pairbuf,
    const int* __restrict__ ptot, int* __restrict__ deg, int* __restrict__ rowstart,
    int* __restrict__ eidx, int n) {
  __shared__ int cnt[1 << BSH];
  __shared__ int scn[1 << BSH];
  __shared__ int lcur[1 << BSH];
  __shared__ int seg[CAP];
  const int b = blockIdx.x;
  const int n0 = b << BSH;
  const int nn = min(1 << BSH, n - n0);
  const int p0 = ptot[b], p1 = ptot[b + 1];
  const int seglen = p1 - p0;
  for (int i = threadIdx.x; i < (1 << BSH); i += BLK) cnt[i] = 0;
  __syncthreads();
  for (int i = p0 + threadIdx.x; i < p1; i += BLK)
    atomicAdd(&cnt[pairbuf[i] >> 17], 1);
  __syncthreads();
  {
    int i0 = threadIdx.x, i1 = threadIdx.x + 256;
    scn[i0] = cnt[i0];
    scn[i1] = cnt[i1];
    __syncthreads();
    for (int off = 1; off < (1 << BSH); off <<= 1) {
      int v0 = (i0 >= off) ? scn[i0 - off] : 0;
      int v1 = (i1 >= off) ? scn[i1 - off] : 0;
      __syncthreads();
      scn[i0] += v0;
      scn[i1] += v1;
      __syncthreads();
    }
  }
  for (int i = threadIdx.x; i < (1 << BSH); i += BLK) {
    int excl = scn[i] - cnt[i];
    lcur[i] = excl;
    if (i < nn) {
      deg[n0 + i] = cnt[i];
      rowstart[n0 + i] = p0 + excl;
    }
  }
  __syncthreads();
  if (seglen <= CAP) {
    for (int i = p0 + threadIdx.x; i < p1; i += BLK) {
      int pk = pairbuf[i];
      int pos = atomicAdd(&lcur[pk >> 17], 1);
      seg[pos] = pk & 0x1FFFF;
    }
    __syncthreads();
    for (int i = threadIdx.x; i < seglen; i += BLK)
      eidx[p0 + i] = seg[i];
  } else {
    for (int i = p0 + threadIdx.x; i < p1; i += BLK) {
      int pk = pairbuf[i];
      int pos = atomicAdd(&lcur[pk >> 17], 1);
      eidx[p0 + pos] = pk & 0x1FFFF;
    }
  }
}

// ---- fused gather-aggregate + residual, depth-2 pipelined ----
template<int C>
__global__ __launch_bounds__(BLK) void agg_kernel(const int* __restrict__ rowstart,
    const int* __restrict__ deg, const int* __restrict__ eidx,
    const float* __restrict__ x, float* __restrict__ out, int n) {
  int gid = blockIdx.x * BLK + threadIdx.x;
  int node, c;
  if constexpr (C == 64) {
    node = __builtin_amdgcn_readfirstlane(gid >> 6);
    c = threadIdx.x & 63;
  } else {
    node = gid / C;
    c = gid & (C - 1);
  }
  if (node >= n) return;
  int s0, d;
  if constexpr (C == 64) {
    s0 = __builtin_amdgcn_readfirstlane(rowstart[node]);
    d  = __builtin_amdgcn_readfirstlane(deg[node]);
  } else {
    s0 = rowstart[node];
    d  = deg[node];
  }
  const float* xc = x + c;
  const int* ep = eidx + s0;
  float den = 0.f, num = 0.f;
  int nq = d >> 2;
  int i0 = 0, i1 = 0, i2 = 0, i3 = 0;
  int j0 = 0, j1 = 0, j2 = 0, j3 = 0;
  if (nq > 0) { i0 = ep[0]; i1 = ep[1]; i2 = ep[2]; i3 = ep[3]; }
  if (nq > 1) { j0 = ep[4]; j1 = ep[5]; j2 = ep[6]; j3 = ep[7]; }
  int q = 0;
  for (; q + 1 < nq; q += 2) {
    float xa = xc[(unsigned)i0 * C];
    float xb = xc[(unsigned)i1 * C];
    float xcv = xc[(unsigned)i2 * C];
    float xd = xc[(unsigned)i3 * C];
    float ya = xc[(unsigned)j0 * C];
    float yb = xc[(unsigned)j1 * C];
    float yc = xc[(unsigned)j2 * C];
    float yd = xc[(unsigned)j3 * C];
    if (q + 2 < nq) {
      const int* p2 = ep + (q + 2) * 4;
      i0 = p2[0]; i1 = p2[1]; i2 = p2[2]; i3 = p2[3];
    }
    if (q + 3 < nq) {
      const int* p3 = ep + (q + 3) * 4;
      j0 = p3[0]; j1 = p3[1]; j2 = p3[2]; j3 = p3[3];
    }
    float ma = fmaxf(xa, 0.f) + F_EPS;
    float mb = fmaxf(xb, 0.f) + F_EPS;
    float mc = fmaxf(xcv, 0.f) + F_EPS;
    float md = fmaxf(xd, 0.f) + F_EPS;
    float na = fmaxf(ya, 0.f) + F_EPS;
    float nb = fmaxf(yb, 0.f) + F_EPS;
    float nc = fmaxf(yc, 0.f) + F_EPS;
    float nd = fmaxf(yd, 0.f) + F_EPS;
    float aa = __expf(ma), ab = __expf(mb), ac = __expf(mc), ad = __expf(md);
    float ba = __expf(na), bb = __expf(nb), bc = __expf(nc), bd = __expf(nd);
    den += ((aa + ab) + (ac + ad)) + ((ba + bb) + (bc + bd));
    num += ((ma * aa + mb * ab) + (mc * ac + md * ad))
         + ((na * ba + nb * bb) + (nc * bc + nd * bd));
  }
  if (q < nq) {
    float xa = xc[(unsigned)i0 * C];
    float xb = xc[(unsigned)i1 * C];
    float xcv = xc[(unsigned)i2 * C];
    float xd = xc[(unsigned)i3 * C];
    float ma = fmaxf(xa, 0.f) + F_EPS;
    float mb = fmaxf(xb, 0.f) + F_EPS;
    float mc = fmaxf(xcv, 0.f) + F_EPS;
    float md = fmaxf(xd, 0.f) + F_EPS;
    float aa = __expf(ma), ab = __expf(mb), ac = __expf(mc), ad = __expf(md);
    den += (aa + ab) + (ac + ad);
    num += (ma * aa + mb * ab) + (mc * ac + md * ad);
  }
  for (int j = nq * 4; j < d; ++j) {
    int sA = ep[j];
    float xa = xc[(unsigned)sA * C];
    float ma = fmaxf(xa, 0.f) + F_EPS;
    float aa = __expf(ma);
    den += aa;
    num += ma * aa;
  }
  float xdv = xc[(unsigned)node * C];
  out[(size_t)node * C + c] = num / (den + 1e-16f) + xdv;
}

// istate: [0]=k remaining [1]=digit [2]=sel count [4]=out count
__global__ void pick0_kernel(int* __restrict__ istate, const int* __restrict__ hist) {
  if (threadIdx.x == 0) {
    int k = TOPK, run = 0;
    for (int d = 255; d >= 0; --d) {
      int c = hist[d];
      if (run + c >= k) { istate[1] = d; istate[0] = k - run; break; }
      run += c;
    }
    istate[2] = 0; istate[4] = 0;
  }
}

__global__ __launch_bounds__(BLK) void compact0_kernel(const u64* __restrict__ in,
    u64* __restrict__ outb, u64* __restrict__ sel, int* __restrict__ istate, int n) {
  int i = blockIdx.x * BLK + threadIdx.x;
  if (i >= n) return;
  u64 kkey = in[i];
  int b = (int)(kkey >> 41);
  int digit = istate[1];
  if (b > digit) {
    sel[atomicAdd(&istate[2], 1)] = kkey;
  } else if (b == digit) {
    outb[atomicAdd(&istate[4], 1)] = kkey;
  }
}

// ---- single block: 5 radix rounds (parallel suffix-scan pick) + rank-order ----
__global__ __launch_bounds__(1024) void topk_finish(u64* __restrict__ bufB,
    u64* __restrict__ bufA, u64* __restrict__ sel, const int* __restrict__ istate,
    const float* __restrict__ scores, int* __restrict__ perm,
    float* __restrict__ gval) {
  __shared__ int hl[512];
  __shared__ int tsum[512];
  __shared__ u64 sk[512];
  __shared__ int sh_digit, sh_k, sh_sel, sh_out, sh_cnt;
  int t = threadIdx.x;
  if (t == 0) { sh_cnt = istate[4]; sh_k = istate[0]; sh_sel = istate[2]; }
  __syncthreads();
  u64* cur = bufB;
  u64* nxt = bufA;
  const int shifts[5] = {33, 25, 17, 9, 0};
  const int masks[5]  = {255, 255, 255, 255, 511};
  for (int r = 0; r < 5; ++r) {
    const int shift = shifts[r], mask = masks[r], wlen = mask + 1;
    for (int i = t; i < wlen; i += 1024) hl[i] = 0;
    __syncthreads();
    int cnt = sh_cnt, krem = sh_k;
    for (int i = t; i < cnt; i += 1024)
      atomicAdd(&hl[(int)(cur[i] >> shift) & mask], 1);
    __syncthreads();
    int v = 0;
    if (t < wlen) { v = hl[t]; tsum[t] = v; }
    __syncthreads();
    for (int off = 1; off < wlen; off <<= 1) {
      int add = 0;
      if (t + off < wlen) add = tsum[t + off];
      __syncthreads();
      if (t + off < wlen) tsum[t] += add;
      __syncthreads();
    }
    if (t < wlen) {
      int T = tsum[t];
      if (T >= krem && (T - v) < krem) {
        sh_digit = t;
        sh_k = krem - (T - v);
      }
    }
    if (t == 0) sh_out = 0;
    __syncthreads();
    int digit = sh_digit;
    for (int i = t; i < cnt; i += 1024) {
      u64 kk = cur[i];
      int b = (int)(kk >> shift) & mask;
      if (b > digit) sel[atomicAdd(&sh_sel, 1)] = kk;
      else if (b == digit) nxt[atomicAdd(&sh_out, 1)] = kk;
    }
    __syncthreads();
    if (t == 0) sh_cnt = sh_out;
    __syncthreads();
    u64* tmp = cur; cur = nxt; nxt = tmp;
  }
  int base = sh_sel, krem = sh_k;
  for (int i = t; i < krem; i += 1024) sel[base + i] = cur[i];
  __syncthreads();
  if (t < 512) sk[t] = sel[t];
  __syncthreads();
  if (t < 512) {
    u64 key = sk[t];
    int rank = 0;
    for (int j = 0; j < 512; ++j) rank += (sk[j] > key) ? 1 : 0;
    int node = 0x1FFFF - (int)(key & 0x1FFFFull);
    perm[rank] = node;
    gval[rank] = scores[node];
  }
}

// ---- grid-wide final gather: out[r] = x[perm[r]] * gval[r] ----
__global__ __launch_bounds__(256) void gather_kernel(const int* __restrict__ perm,
    const float* __restrict__ gval, const float* __restrict__ x,
    float* __restrict__ out) {
  int i = blockIdx.x * 256 + threadIdx.x;
  int r = i >> 4, c = i & 15;
  int node = perm[r];
  float v = gval[r];
  float4 xv = reinterpret_cast<const float4*>(x)[(size_t)node * 16 + c];
  float4 o; o.x = xv.x * v; o.y = xv.y * v; o.z = xv.z * v; o.w = xv.w * v;
  reinterpret_cast<float4*>(out)[(size_t)r * 16 + c] = o;
}

extern "C" void kernel_launch(void* const* d_in, const int* in_sizes, int n_in,
                              void* d_out, int out_size, void* d_ws, size_t ws_size,
                              hipStream_t stream) {
  const int N = in_sizes[0] / 3;
  const int E = in_sizes[1] / 2;

  const float* pos   = (const float*)d_in[0];
  const int*   ei    = (const int*)d_in[1];
  const int*   src   = ei;
  const int*   dst   = ei + E;
  const float* c1_lw = (const float*)d_in[2];
  const float* c1_lb = (const float*)d_in[3];
  const float* c1_w1 = (const float*)d_in[4];
  const float* c1_b1 = (const float*)d_in[5];
  const float* c1_g1 = (const float*)d_in[6];
  const float* c1_be1= (const float*)d_in[7];
  const float* c1_w2 = (const float*)d_in[8];
  const float* c1_b2 = (const float*)d_in[9];
  const float* c2_lw = (const float*)d_in[10];
  const float* c2_lb = (const float*)d_in[11];
  const float* c2_w1 = (const float*)d_in[12];
  const float* c2_b1 = (const float*)d_in[13];
  const float* c2_g1 = (const float*)d_in[14];
  const float* c2_be1= (const float*)d_in[15];
  const float* c2_w2 = (const float*)d_in[16];
  const float* c2_b2 = (const float*)d_in[17];
  const float* poolw = (const float*)d_in[18];

  // ---- workspace layout ----
  float* ws = (float*)d_ws;
  float* x1   = ws;                         // 16N
  float* h1   = ws + (size_t)16 * N;        // 32N
  float* o1   = ws + (size_t)48 * N;        // 16N
  float* res2 = ws;                         // 64N
  float* x2   = ws + (size_t)64 * N;        // 64N
  float* res1 = x2;                         // 16N
  float* h2   = ws + (size_t)128 * N;       // 128N
  float* o2   = ws + (size_t)256 * N;       // 64N
  float* scores = ws + (size_t)320 * N;     // N
  u64* candA = (u64*)(ws + (size_t)321 * N);            // N
  u64* candB = candA + N;                               // N
  u64* sel   = candB + N;                               // 512
  double* partial = (double*)(sel + TOPK);              // 4 MB reserved
  int* ibase   = (int*)(partial + (size_t)524288);
  int* istate  = ibase;            // 8
  int* hist    = ibase + 8;        // 256
  int* perm    = ibase + 776;      // 512
  float* gval  = (float*)(ibase + 1288);    // 512
  int* deg     = ibase + 1800;     // N
  int* rowstart= deg + N;          // N
  int* eidx    = rowstart + N;     // E
  int* pairbuf = eidx + E;         // E
  int* pcnt    = pairbuf + E;      // PA*MAXBUK
  int* poff    = pcnt + PA * MAXBUK;  // PA*MAXBUK
  int* ptot    = poff + PA * MAXBUK;  // MAXBUK+1
  float* fsc   = (float*)(ptot + MAXBUK + 1);
  float* sc1 = fsc;        float* sh1 = fsc + 32;
  float* sc2 = fsc + 64;   float* sh2 = fsc + 192;     // 320 floats total

  const int nbN = (N + BLK - 1) / BLK;
  const int nbG = (N + 63) / 64;
  const int NBUK = (N + (1 << BSH) - 1) >> BSH;
  const int chunk = (E + PA - 1) / PA;

  // replay-safe zeroing: istate/hist are atomic accumulation targets
  hipMemsetAsync(ibase, 0, 1800 * sizeof(int), stream);

  // ---- CSR build (atomic-free: counting sort; deg/rowstart derived in LDS) ----
  pcount_kernel<<<PA, BLK, 0, stream>>>(dst, pcnt, E, chunk);
  pscan_kernel<<<1, 256, 0, stream>>>(pcnt, poff, ptot, PA, NBUK);
  ppack_kernel<<<PA, BLK, 0, stream>>>(src, dst, poff, ptot, pairbuf, E, chunk);
  place_kernel<<<NBUK, BLK, 0, stream>>>(pairbuf, ptot, deg, rowstart, eidx, N);

  // ---- conv1 ----
  lin_kernel<3, 16, 16><<<dim3(nbN, 1), BLK, 0, stream>>>(pos, c1_lw, c1_lb, x1, nullptr, N);
  agg_kernel<16><<<(N * 16 + BLK - 1) / BLK, BLK, 0, stream>>>(rowstart, deg, eidx, x1, res1, N);
  lin_kernel<16, 32, 32, true><<<dim3(nbN, 1), BLK, 0, stream>>>(res1, c1_w1, c1_b1, h1, partial, N);
  bn_fin3<32, 32><<<32, 256, 0, stream>>>(partial, c1_g1, c1_be1, sc1, sh1, N, nbN);
  mlp2_kernel<32, 16, 16><<<dim3(nbN, 1), BLK, 0, stream>>>(h1, sc1, sh1, c1_w2, c1_b2, o1, N);

  // ---- conv2 ----
  gemm_tile<16, 64, 4, false, false, false, false><<<nbG, 256, 0, stream>>>(
      o1, c2_lw, c2_lb, nullptr, nullptr, x2, nullptr,
      nullptr, nullptr, nullptr, nullptr, N);
  agg_kernel<64><<<(N * 64 + BLK - 1) / BLK, BLK, 0, stream>>>(rowstart, deg, eidx, x2, res2, N);
  gemm_tile<64, 128, 4, false, false, true, false><<<nbG, 256, 0, stream>>>(
      res2, c2_w1, c2_b1, nullptr, nullptr, h2, partial,
      nullptr, nullptr, nullptr, nullptr, N);
  bn_fin_ws<128><<<128, 256, 0, stream>>>(partial, c2_g1, c2_be1, sc2, sh2, N, nbG);
  // last GEMM: fused BN-input + leaky + TopK scoring (scores/keys/hist)
  gemm_tile<128, 64, 4, true, true, false, true><<<nbG, 256, 0, stream>>>(
      h2, c2_w2, c2_b2, sc2, sh2, o2, nullptr,
      poolw, scores, candA, hist, N);

  // ---- exact top-K ----
  pick0_kernel<<<1, 64, 0, stream>>>(istate, hist);
  compact0_kernel<<<nbN, BLK, 0, stream>>>(candA, candB, sel, istate, N);
  topk_finish<<<1, 1024, 0, stream>>>(candB, candA, sel, istate, scores, perm, gval);
  gather_kernel<<<32, 256, 0, stream>>>(perm, gval, o2, (float*)d_out);

  (void)n_in; (void)out_size; (void)ws_size;
}

// Round 25
// 338.846 us; speedup vs baseline: 1.0203x; 1.0203x over previous
//
#include <hip/hip_runtime.h>
#include <stdint.h>

#define BLK 256

static constexpr float F_EPS = 1e-7f;   // GENConv message eps
static constexpr float F_NEG = 0.01f;   // LeakyReLU slope
static constexpr int   TOPK  = 512;
static constexpr int   PA    = 128;     // pcount/ppack grid
static constexpr int   BSH   = 9;       // bucket = dst >> 9 (512 nodes)
static constexpr int   MAXBUK= 256;     // bucket stride (N/512 <= 256)
static constexpr int   CAP   = 8192;    // LDS segment capacity (entries)

typedef unsigned long long u64;

__device__ __forceinline__ unsigned int ord_f32(float f) {
  unsigned int u = __float_as_uint(f);
  return (u & 0x80000000u) ? ~u : (u | 0x80000000u);
}

// ======== register-blocked GEMM tile: block = [NODES=16*TM nodes] x [COUT] ====
template<int CIN, int COUT, int TM, bool BN, bool LEAKY, bool STAT>
__global__ __launch_bounds__(256) void gemm_tile(const float* __restrict__ in,
    const float* __restrict__ W, const float* __restrict__ b,
    const float* __restrict__ scale, const float* __restrict__ shift,
    float* __restrict__ out, double* __restrict__ partial, int n) {
  constexpr int TN = COUT / 16;
  constexpr int NODES = 16 * TM;
  constexpr int KC = (CIN > 64) ? 64 : CIN;
  constexpr int NPAD = NODES + 4;
  __shared__ float xs[KC][NPAD];
  __shared__ float wsh[CIN * COUT];
  __shared__ float sB[COUT];
  __shared__ float sSc[BN ? CIN : 4];
  __shared__ float sSh[BN ? CIN : 4];
  for (int i = threadIdx.x; i < CIN * COUT; i += 256) wsh[i] = W[i];
  for (int i = threadIdx.x; i < COUT; i += 256) sB[i] = b[i];
  if constexpr (BN) {
    for (int i = threadIdx.x; i < CIN; i += 256) { sSc[i] = scale[i]; sSh[i] = shift[i]; }
  }
  __syncthreads();
  const int tn = threadIdx.x & 15;
  const int tj = threadIdx.x >> 4;
  const int node0 = blockIdx.x * NODES;

  float acc[TM][TN];
  #pragma unroll
  for (int m = 0; m < TM; ++m)
    #pragma unroll
    for (int j = 0; j < TN; ++j) acc[m][j] = sB[tj * TN + j];

  for (int kc = 0; kc < CIN; kc += KC) {
    __syncthreads();
    constexpr int NL = NODES * (KC / 4);
    for (int i = threadIdx.x; i < NL; i += 256) {
      int nd = i / (KC / 4);
      int kq = i - nd * (KC / 4);
      int gn = node0 + nd;
      const float* p = in + (size_t)(gn < n ? gn : n - 1) * CIN + kc + kq * 4;
      float4 v = *reinterpret_cast<const float4*>(p);
      if constexpr (BN) {
        int kb = kc + kq * 4;
        v.x = fmaxf(v.x * sSc[kb+0] + sSh[kb+0], 0.f);
        v.y = fmaxf(v.y * sSc[kb+1] + sSh[kb+1], 0.f);
        v.z = fmaxf(v.z * sSc[kb+2] + sSh[kb+2], 0.f);
        v.w = fmaxf(v.w * sSc[kb+3] + sSh[kb+3], 0.f);
      }
      xs[kq*4+0][nd] = v.x; xs[kq*4+1][nd] = v.y;
      xs[kq*4+2][nd] = v.z; xs[kq*4+3][nd] = v.w;
    }
    __syncthreads();
    #pragma unroll 16
    for (int k = 0; k < KC; ++k) {
      float xv[TM], wv[TN];
      #pragma unroll
      for (int m = 0; m < TM; ++m) xv[m] = xs[k][tn * TM + m];
      #pragma unroll
      for (int j = 0; j < TN; ++j) wv[j] = wsh[(kc + k) * COUT + tj * TN + j];
      #pragma unroll
      for (int m = 0; m < TM; ++m)
        #pragma unroll
        for (int j = 0; j < TN; ++j)
          acc[m][j] += xv[m] * wv[j];
    }
  }
  #pragma unroll
  for (int m = 0; m < TM; ++m) {
    int gn = node0 + tn * TM + m;
    if (gn < n) {
      float* orow = out + (size_t)gn * COUT + tj * TN;
      #pragma unroll
      for (int j = 0; j < TN; j += 4) {
        float a0 = acc[m][j], a1 = acc[m][j+1], a2 = acc[m][j+2], a3 = acc[m][j+3];
        if constexpr (LEAKY) {
          a0 = a0 > 0.f ? a0 : F_NEG * a0;
          a1 = a1 > 0.f ? a1 : F_NEG * a1;
          a2 = a2 > 0.f ? a2 : F_NEG * a2;
          a3 = a3 > 0.f ? a3 : F_NEG * a3;
        }
        float4 r; r.x = a0; r.y = a1; r.z = a2; r.w = a3;
        *reinterpret_cast<float4*>(orow + j) = r;
      }
    }
  }
  if constexpr (STAT) {
    __shared__ double sStat[2 * COUT];
    double sv[TN], qv[TN];
    #pragma unroll
    for (int j = 0; j < TN; ++j) { sv[j] = 0.0; qv[j] = 0.0; }
    #pragma unroll
    for (int m = 0; m < TM; ++m) {
      bool v = (node0 + tn * TM + m) < n;
      #pragma unroll
      for (int j = 0; j < TN; ++j) {
        double a = v ? (double)acc[m][j] : 0.0;
        sv[j] += a; qv[j] += a * a;
      }
    }
    #pragma unroll
    for (int j = 0; j < TN; ++j) {
      for (int off = 8; off; off >>= 1) {
        sv[j] += __shfl_down(sv[j], off, 16);
        qv[j] += __shfl_down(qv[j], off, 16);
      }
    }
    if (tn == 0) {
      #pragma unroll
      for (int j = 0; j < TN; ++j) {
        sStat[tj * TN + j] = sv[j];
        sStat[COUT + tj * TN + j] = qv[j];
      }
    }
    __syncthreads();
    for (int i = threadIdx.x; i < 2 * COUT; i += 256)
      partial[(size_t)blockIdx.x * (2 * COUT) + i] = sStat[i];
  }
}

// ---- BN finalize for gemm_tile partials ----
template<int COUT>
__global__ __launch_bounds__(256) void bn_fin_ws(const double* __restrict__ partial,
    const float* __restrict__ g, const float* __restrict__ be,
    float* __restrict__ sc, float* __restrict__ sh, int n, int nbx) {
  int j = blockIdx.x;
  int t = threadIdx.x;
  double s = 0, q = 0;
  for (int bdx = t; bdx < nbx; bdx += 256) {
    s += partial[(size_t)bdx * (2 * COUT) + j];
    q += partial[(size_t)bdx * (2 * COUT) + COUT + j];
  }
  for (int off = 32; off; off >>= 1) { s += __shfl_down(s, off); q += __shfl_down(q, off); }
  __shared__ double sw[4][2];
  int lane = t & 63, wid = t >> 6;
  if (lane == 0) { sw[wid][0] = s; sw[wid][1] = q; }
  __syncthreads();
  if (t == 0) {
    s = sw[0][0] + sw[1][0] + sw[2][0] + sw[3][0];
    q = sw[0][1] + sw[1][1] + sw[2][1] + sw[3][1];
    double inv_n = 1.0 / (double)n;
    double mu = s * inv_n;
    double var = q * inv_n - mu * mu;
    double scd = (double)g[j] / sqrt(var + 1e-5);
    sc[j] = (float)scd;
    sh[j] = (float)((double)be[j] - mu * scd);
  }
}

// ------- column-tiled dense (conv1 small layers) -------
template<int CIN, int COUT, int JT, bool STAT = false>
__global__ __launch_bounds__(BLK) void lin_kernel(const float* __restrict__ in,
    const float* __restrict__ W, const float* __restrict__ b,
    float* __restrict__ out, double* __restrict__ partial, int n) {
  __shared__ float sW[CIN * JT];
  __shared__ float sB[JT];
  const int j0 = blockIdx.y * JT;
  for (int i = threadIdx.x; i < CIN * JT; i += BLK) {
    int k = i / JT, jj = i - k * JT;
    sW[i] = W[k * COUT + j0 + jj];
  }
  for (int i = threadIdx.x; i < JT; i += BLK) sB[i] = b[j0 + i];
  __syncthreads();
  int node = blockIdx.x * BLK + threadIdx.x;
  bool valid = node < n;
  if constexpr (!STAT) { if (!valid) return; }
  int rnode = valid ? node : (n - 1);
  float acc[JT];
  #pragma unroll
  for (int jj = 0; jj < JT; ++jj) acc[jj] = sB[jj];
  const float* xrow = in + (size_t)rnode * CIN;
  if constexpr ((CIN & 3) == 0) {
    float x[CIN];
    #pragma unroll
    for (int k4 = 0; k4 < CIN / 4; ++k4) {
      float4 v = *reinterpret_cast<const float4*>(xrow + k4 * 4);
      x[4*k4+0] = v.x; x[4*k4+1] = v.y; x[4*k4+2] = v.z; x[4*k4+3] = v.w;
    }
    #pragma unroll
    for (int k = 0; k < CIN; ++k) {
      #pragma unroll
      for (int jj = 0; jj < JT; ++jj)
        acc[jj] += x[k] * sW[k * JT + jj];
    }
  } else {
    #pragma unroll
    for (int k = 0; k < CIN; ++k) {
      float xv = xrow[k];
      #pragma unroll
      for (int jj = 0; jj < JT; ++jj)
        acc[jj] += xv * sW[k * JT + jj];
    }
  }
  if (valid) {
    float* orow = out + (size_t)node * COUT + j0;
    #pragma unroll
    for (int jj = 0; jj < JT; jj += 4) {
      float4 r; r.x = acc[jj]; r.y = acc[jj+1]; r.z = acc[jj+2]; r.w = acc[jj+3];
      *reinterpret_cast<float4*>(orow + jj) = r;
    }
  }
  if constexpr (STAT) {
    __shared__ double sStat[4][2 * JT];
    int lane = threadIdx.x & 63, wid = threadIdx.x >> 6;
    #pragma unroll
    for (int jj = 0; jj < JT; ++jj) {
      double sv = valid ? (double)acc[jj] : 0.0;
      double qv = sv * sv;
      for (int off = 32; off; off >>= 1) {
        sv += __shfl_down(sv, off);
        qv += __shfl_down(qv, off);
      }
      if (lane == 0) { sStat[wid][jj] = sv; sStat[wid][JT + jj] = qv; }
    }
    __syncthreads();
    if (threadIdx.x < 2 * JT) {
      double v = sStat[0][threadIdx.x] + sStat[1][threadIdx.x]
               + sStat[2][threadIdx.x] + sStat[3][threadIdx.x];
      partial[((size_t)blockIdx.y * gridDim.x + blockIdx.x) * (2 * JT) + threadIdx.x] = v;
    }
  }
}

// ---- BN finalize for lin_kernel partials (conv1 path) ----
template<int COUT, int JT>
__global__ __launch_bounds__(256) void bn_fin3(const double* __restrict__ partial,
    const float* __restrict__ g, const float* __restrict__ be,
    float* __restrict__ sc, float* __restrict__ sh, int n, int nbx) {
  int j = blockIdx.x;
  int t = threadIdx.x;
  int jt = j / JT, jj = j - jt * JT;
  double s = 0, q = 0;
  for (int b = t; b < nbx; b += 256) {
    const double* row = partial + ((size_t)jt * nbx + b) * (2 * JT);
    s += row[jj];
    q += row[JT + jj];
  }
  for (int off = 32; off; off >>= 1) { s += __shfl_down(s, off); q += __shfl_down(q, off); }
  __shared__ double sw[4][2];
  int lane = t & 63, wid = t >> 6;
  if (lane == 0) { sw[wid][0] = s; sw[wid][1] = q; }
  __syncthreads();
  if (t == 0) {
    s = sw[0][0] + sw[1][0] + sw[2][0] + sw[3][0];
    q = sw[0][1] + sw[1][1] + sw[2][1] + sw[3][1];
    double inv_n = 1.0 / (double)n;
    double mu = s * inv_n;
    double var = q * inv_n - mu * mu;
    double scd = (double)g[j] / sqrt(var + 1e-5);
    sc[j] = (float)scd;
    sh[j] = (float)((double)be[j] - mu * scd);
  }
}

// ---- conv1 MLP second half: t=relu(h*sc+sh); out=leaky(t@W+b) ----
template<int CIN, int COUT, int JT>
__global__ __launch_bounds__(BLK) void mlp2_kernel(const float* __restrict__ h,
    const float* __restrict__ scale, const float* __restrict__ shift,
    const float* __restrict__ W, const float* __restrict__ b,
    float* __restrict__ out, int n) {
  __shared__ float sW[CIN * JT];
  __shared__ float sB[JT];
  __shared__ float sSc[CIN];
  __shared__ float sSh[CIN];
  const int j0 = blockIdx.y * JT;
  for (int i = threadIdx.x; i < CIN * JT; i += BLK) {
    int k = i / JT, jj = i - k * JT;
    sW[i] = W[k * COUT + j0 + jj];
  }
  for (int i = threadIdx.x; i < JT; i += BLK) sB[i] = b[j0 + i];
  for (int i = threadIdx.x; i < CIN; i += BLK) { sSc[i] = scale[i]; sSh[i] = shift[i]; }
  __syncthreads();
  int node = blockIdx.x * BLK + threadIdx.x;
  if (node >= n) return;
  float acc[JT];
  #pragma unroll
  for (int jj = 0; jj < JT; ++jj) acc[jj] = sB[jj];
  const float* xrow = h + (size_t)node * CIN;
  float x[CIN];
  #pragma unroll
  for (int k4 = 0; k4 < CIN / 4; ++k4) {
    float4 v = *reinterpret_cast<const float4*>(xrow + k4 * 4);
    x[4*k4+0] = fmaxf(v.x * sSc[4*k4+0] + sSh[4*k4+0], 0.f);
    x[4*k4+1] = fmaxf(v.y * sSc[4*k4+1] + sSh[4*k4+1], 0.f);
    x[4*k4+2] = fmaxf(v.z * sSc[4*k4+2] + sSh[4*k4+2], 0.f);
    x[4*k4+3] = fmaxf(v.w * sSc[4*k4+3] + sSh[4*k4+3], 0.f);
  }
  #pragma unroll
  for (int k = 0; k < CIN; ++k) {
    #pragma unroll
    for (int jj = 0; jj < JT; ++jj)
      acc[jj] += x[k] * sW[k * JT + jj];
  }
  float* orow = out + (size_t)node * COUT + j0;
  #pragma unroll
  for (int jj = 0; jj < JT; jj += 4) {
    float a0 = acc[jj], a1 = acc[jj+1], a2 = acc[jj+2], a3 = acc[jj+3];
    a0 = a0 > 0.f ? a0 : F_NEG * a0;
    a1 = a1 > 0.f ? a1 : F_NEG * a1;
    a2 = a2 > 0.f ? a2 : F_NEG * a2;
    a3 = a3 > 0.f ? a3 : F_NEG * a3;
    float4 r; r.x = a0; r.y = a1; r.z = a2; r.w = a3;
    *reinterpret_cast<float4*>(orow + jj) = r;
  }
}

// ---------------- CSR build (atomic-free, bucket counting sort) ----------------
__global__ __launch_bounds__(BLK) void pcount_kernel(const int* __restrict__ dst,
    int* __restrict__ pcnt, int E, int chunk) {
  __shared__ int cb[MAXBUK];
  for (int i = threadIdx.x; i < MAXBUK; i += BLK) cb[i] = 0;
  __syncthreads();
  int e0 = blockIdx.x * chunk;
  int e1 = min(e0 + chunk, E);
  for (int e = e0 + threadIdx.x; e < e1; e += BLK)
    atomicAdd(&cb[dst[e] >> BSH], 1);
  __syncthreads();
  for (int i = threadIdx.x; i < MAXBUK; i += BLK)
    pcnt[blockIdx.x * MAXBUK + i] = cb[i];
}

__global__ __launch_bounds__(256) void pscan_kernel(const int* __restrict__ pcnt,
    int* __restrict__ poff, int* __restrict__ ptot, int nblk, int nbuk) {
  __shared__ int s[256];
  __shared__ int tot[256];
  int t = threadIdx.x;
  int sum = 0;
  if (t < nbuk) {
    for (int blk = 0; blk < nblk; ++blk) {
      int v = pcnt[blk * MAXBUK + t];
      poff[blk * MAXBUK + t] = sum;
      sum += v;
    }
  }
  tot[t] = (t < nbuk) ? sum : 0;
  s[t] = tot[t];
  __syncthreads();
  for (int off = 1; off < 256; off <<= 1) {
    int add = (t >= off) ? s[t - off] : 0;
    __syncthreads();
    s[t] += add;
    __syncthreads();
  }
  if (t < nbuk) ptot[t] = s[t] - tot[t];   // exclusive base
  if (t == 0) ptot[nbuk] = s[255];
}

__global__ __launch_bounds__(BLK) void ppack_kernel(const int* __restrict__ src,
    const int* __restrict__ dst, const int* __restrict__ poff,
    const int* __restrict__ ptot, int* __restrict__ pairbuf, int E, int chunk) {
  __shared__ int cb[MAXBUK];
  for (int i = threadIdx.x; i < MAXBUK; i += BLK)
    cb[i] = ptot[i] + poff[blockIdx.x * MAXBUK + i];
  __syncthreads();
  int e0 = blockIdx.x * chunk;
  int e1 = min(e0 + chunk, E);
  for (int e = e0 + threadIdx.x; e < e1; e += BLK) {
    int d = dst[e], sv = src[e];
    int b = d >> BSH;
    int pos = atomicAdd(&cb[b], 1);
    pairbuf[pos] = ((d & ((1 << BSH) - 1)) << 17) | sv;
  }
}

__global__ __launch_bounds__(BLK) void place_kernel(const int* __restrict__ pairbuf,
    const int* __restrict__ ptot, int* __restrict__ deg, int* __restrict__ rowstart,
    int* __restrict__ eidx, int n) {
  __shared__ int cnt[1 << BSH];
  __shared__ int scn[1 << BSH];
  __shared__ int lcur[1 << BSH];
  __shared__ int seg[CAP];
  const int b = blockIdx.x;
  const int n0 = b << BSH;
  const int nn = min(1 << BSH, n - n0);
  const int p0 = ptot[b], p1 = ptot[b + 1];
  const int seglen = p1 - p0;
  for (int i = threadIdx.x; i < (1 << BSH); i += BLK) cnt[i] = 0;
  __syncthreads();
  for (int i = p0 + threadIdx.x; i < p1; i += BLK)
    atomicAdd(&cnt[pairbuf[i] >> 17], 1);
  __syncthreads();
  {
    int i0 = threadIdx.x, i1 = threadIdx.x + 256;
    scn[i0] = cnt[i0];
    scn[i1] = cnt[i1];
    __syncthreads();
    for (int off = 1; off < (1 << BSH); off <<= 1) {
      int v0 = (i0 >= off) ? scn[i0 - off] : 0;
      int v1 = (i1 >= off) ? scn[i1 - off] : 0;
      __syncthreads();
      scn[i0] += v0;
      scn[i1] += v1;
      __syncthreads();
    }
  }
  for (int i = threadIdx.x; i < (1 << BSH); i += BLK) {
    int excl = scn[i] - cnt[i];
    lcur[i] = excl;
    if (i < nn) {
      deg[n0 + i] = cnt[i];
      rowstart[n0 + i] = p0 + excl;
    }
  }
  __syncthreads();
  if (seglen <= CAP) {
    for (int i = p0 + threadIdx.x; i < p1; i += BLK) {
      int pk = pairbuf[i];
      int pos = atomicAdd(&lcur[pk >> 17], 1);
      seg[pos] = pk & 0x1FFFF;
    }
    __syncthreads();
    for (int i = threadIdx.x; i < seglen; i += BLK)
      eidx[p0 + i] = seg[i];
  } else {
    for (int i = p0 + threadIdx.x; i < p1; i += BLK) {
      int pk = pairbuf[i];
      int pos = atomicAdd(&lcur[pk >> 17], 1);
      eidx[p0 + pos] = pk & 0x1FFFF;
    }
  }
}

// ---- fused gather-aggregate + residual, depth-2 pipelined ----
template<int C>
__global__ __launch_bounds__(BLK) void agg_kernel(const int* __restrict__ rowstart,
    const int* __restrict__ deg, const int* __restrict__ eidx,
    const float* __restrict__ x, float* __restrict__ out, int n) {
  int gid = blockIdx.x * BLK + threadIdx.x;
  int node, c;
  if constexpr (C == 64) {
    node = __builtin_amdgcn_readfirstlane(gid >> 6);
    c = threadIdx.x & 63;
  } else {
    node = gid / C;
    c = gid & (C - 1);
  }
  if (node >= n) return;
  int s0, d;
  if constexpr (C == 64) {
    s0 = __builtin_amdgcn_readfirstlane(rowstart[node]);
    d  = __builtin_amdgcn_readfirstlane(deg[node]);
  } else {
    s0 = rowstart[node];
    d  = deg[node];
  }
  const float* xc = x + c;
  const int* ep = eidx + s0;
  float den = 0.f, num = 0.f;
  int nq = d >> 2;
  int i0 = 0, i1 = 0, i2 = 0, i3 = 0;
  int j0 = 0, j1 = 0, j2 = 0, j3 = 0;
  if (nq > 0) { i0 = ep[0]; i1 = ep[1]; i2 = ep[2]; i3 = ep[3]; }
  if (nq > 1) { j0 = ep[4]; j1 = ep[5]; j2 = ep[6]; j3 = ep[7]; }
  int q = 0;
  for (; q + 1 < nq; q += 2) {
    float xa = xc[(unsigned)i0 * C];
    float xb = xc[(unsigned)i1 * C];
    float xcv = xc[(unsigned)i2 * C];
    float xd = xc[(unsigned)i3 * C];
    float ya = xc[(unsigned)j0 * C];
    float yb = xc[(unsigned)j1 * C];
    float yc = xc[(unsigned)j2 * C];
    float yd = xc[(unsigned)j3 * C];
    if (q + 2 < nq) {
      const int* p2 = ep + (q + 2) * 4;
      i0 = p2[0]; i1 = p2[1]; i2 = p2[2]; i3 = p2[3];
    }
    if (q + 3 < nq) {
      const int* p3 = ep + (q + 3) * 4;
      j0 = p3[0]; j1 = p3[1]; j2 = p3[2]; j3 = p3[3];
    }
    float ma = fmaxf(xa, 0.f) + F_EPS;
    float mb = fmaxf(xb, 0.f) + F_EPS;
    float mc = fmaxf(xcv, 0.f) + F_EPS;
    float md = fmaxf(xd, 0.f) + F_EPS;
    float na = fmaxf(ya, 0.f) + F_EPS;
    float nb = fmaxf(yb, 0.f) + F_EPS;
    float nc = fmaxf(yc, 0.f) + F_EPS;
    float nd = fmaxf(yd, 0.f) + F_EPS;
    float aa = __expf(ma), ab = __expf(mb), ac = __expf(mc), ad = __expf(md);
    float ba = __expf(na), bb = __expf(nb), bc = __expf(nc), bd = __expf(nd);
    den += ((aa + ab) + (ac + ad)) + ((ba + bb) + (bc + bd));
    num += ((ma * aa + mb * ab) + (mc * ac + md * ad))
         + ((na * ba + nb * bb) + (nc * bc + nd * bd));
  }
  if (q < nq) {
    float xa = xc[(unsigned)i0 * C];
    float xb = xc[(unsigned)i1 * C];
    float xcv = xc[(unsigned)i2 * C];
    float xd = xc[(unsigned)i3 * C];
    float ma = fmaxf(xa, 0.f) + F_EPS;
    float mb = fmaxf(xb, 0.f) + F_EPS;
    float mc = fmaxf(xcv, 0.f) + F_EPS;
    float md = fmaxf(xd, 0.f) + F_EPS;
    float aa = __expf(ma), ab = __expf(mb), ac = __expf(mc), ad = __expf(md);
    den += (aa + ab) + (ac + ad);
    num += (ma * aa + mb * ab) + (mc * ac + md * ad);
  }
  for (int j = nq * 4; j < d; ++j) {
    int sA = ep[j];
    float xa = xc[(unsigned)sA * C];
    float ma = fmaxf(xa, 0.f) + F_EPS;
    float aa = __expf(ma);
    den += aa;
    num += ma * aa;
  }
  float xdv = xc[(unsigned)node * C];
  out[(size_t)node * C + c] = num / (den + 1e-16f) + xdv;
}

// ---- score + 49-bit key + round-0 histogram (bits 48..41) ----
__global__ __launch_bounds__(BLK) void score_kernel(const float* __restrict__ x,
    const float* __restrict__ w, float* __restrict__ scores,
    u64* __restrict__ keys, int* __restrict__ ghist, int n) {
  __shared__ float sw[64];
  __shared__ float snorm;
  __shared__ int hl[256];
  if (threadIdx.x < 64) sw[threadIdx.x] = w[threadIdx.x];
  hl[threadIdx.x] = 0;
  __syncthreads();
  if (threadIdx.x < 64) {
    float v = sw[threadIdx.x];
    float sq = v * v;
    for (int off = 32; off; off >>= 1) sq += __shfl_down(sq, off);
    if (threadIdx.x == 0) snorm = 1.f / sqrtf(sq);
  }
  __syncthreads();
  int node = blockIdx.x * BLK + threadIdx.x;
  if (node < n) {
    const float4* row = reinterpret_cast<const float4*>(x + (size_t)node * 64);
    float acc = 0.f;
    #pragma unroll
    for (int k4 = 0; k4 < 16; ++k4) {
      float4 v = row[k4];
      const float4 wv = *reinterpret_cast<const float4*>(&sw[4 * k4]);
      acc += v.x * wv.x + v.y * wv.y + v.z * wv.z + v.w * wv.w;
    }
    float s = tanhf(acc * snorm);
    scores[node] = s;
    u64 key = ((u64)ord_f32(s) << 17) | (u64)(0x1FFFF - node);
    keys[node] = key;
    atomicAdd(&hl[(int)(key >> 41)], 1);
  }
  __syncthreads();
  int v = hl[threadIdx.x];
  if (v) atomicAdd(&ghist[threadIdx.x], v);
}

// ---- compact0 with fused digit-pick (each block derives digit from hist;
// block 0 persists istate[0]=k_rem, istate[1]=digit for topk_finish) ----
__global__ __launch_bounds__(BLK) void compact0_kernel(const u64* __restrict__ in,
    u64* __restrict__ outb, u64* __restrict__ sel, int* __restrict__ istate,
    const int* __restrict__ hist, int n) {
  __shared__ int sh_digit;
  if (threadIdx.x == 0) {
    int k = TOPK, run = 0, dsel = 0, krem = TOPK;
    for (int d = 255; d >= 0; --d) {
      int c = hist[d];
      if (run + c >= k) { dsel = d; krem = k - run; break; }
      run += c;
    }
    sh_digit = dsel;
    if (blockIdx.x == 0) { istate[0] = krem; istate[1] = dsel; }
  }
  __syncthreads();
  int digit = sh_digit;
  int i = blockIdx.x * BLK + threadIdx.x;
  if (i >= n) return;
  u64 kkey = in[i];
  int b = (int)(kkey >> 41);
  if (b > digit) {
    sel[atomicAdd(&istate[2], 1)] = kkey;
  } else if (b == digit) {
    outb[atomicAdd(&istate[4], 1)] = kkey;
  }
}

// ---- single block: 5 radix rounds (parallel suffix-scan pick) + rank-order ----
__global__ __launch_bounds__(1024) void topk_finish(u64* __restrict__ bufB,
    u64* __restrict__ bufA, u64* __restrict__ sel, const int* __restrict__ istate,
    const float* __restrict__ scores, int* __restrict__ perm,
    float* __restrict__ gval) {
  __shared__ int hl[512];
  __shared__ int tsum[512];
  __shared__ u64 sk[512];
  __shared__ int sh_digit, sh_k, sh_sel, sh_out, sh_cnt;
  int t = threadIdx.x;
  if (t == 0) { sh_cnt = istate[4]; sh_k = istate[0]; sh_sel = istate[2]; }
  __syncthreads();
  u64* cur = bufB;
  u64* nxt = bufA;
  const int shifts[5] = {33, 25, 17, 9, 0};
  const int masks[5]  = {255, 255, 255, 255, 511};
  for (int r = 0; r < 5; ++r) {
    const int shift = shifts[r], mask = masks[r], wlen = mask + 1;
    for (int i = t; i < wlen; i += 1024) hl[i] = 0;
    __syncthreads();
    int cnt = sh_cnt, krem = sh_k;
    for (int i = t; i < cnt; i += 1024)
      atomicAdd(&hl[(int)(cur[i] >> shift) & mask], 1);
    __syncthreads();
    int v = 0;
    if (t < wlen) { v = hl[t]; tsum[t] = v; }
    __syncthreads();
    for (int off = 1; off < wlen; off <<= 1) {
      int add = 0;
      if (t + off < wlen) add = tsum[t + off];
      __syncthreads();
      if (t + off < wlen) tsum[t] += add;
      __syncthreads();
    }
    if (t < wlen) {
      int T = tsum[t];
      if (T >= krem && (T - v) < krem) {
        sh_digit = t;
        sh_k = krem - (T - v);
      }
    }
    if (t == 0) sh_out = 0;
    __syncthreads();
    int digit = sh_digit;
    for (int i = t; i < cnt; i += 1024) {
      u64 kk = cur[i];
      int b = (int)(kk >> shift) & mask;
      if (b > digit) sel[atomicAdd(&sh_sel, 1)] = kk;
      else if (b == digit) nxt[atomicAdd(&sh_out, 1)] = kk;
    }
    __syncthreads();
    if (t == 0) sh_cnt = sh_out;
    __syncthreads();
    u64* tmp = cur; cur = nxt; nxt = tmp;
  }
  int base = sh_sel, krem = sh_k;
  for (int i = t; i < krem; i += 1024) sel[base + i] = cur[i];
  __syncthreads();
  if (t < 512) sk[t] = sel[t];
  __syncthreads();
  if (t < 512) {
    u64 key = sk[t];
    int rank = 0;
    for (int j = 0; j < 512; ++j) rank += (sk[j] > key) ? 1 : 0;
    int node = 0x1FFFF - (int)(key & 0x1FFFFull);
    perm[rank] = node;
    gval[rank] = scores[node];
  }
}

// ---- grid-wide final gather: out[r] = x[perm[r]] * gval[r] ----
__global__ __launch_bounds__(256) void gather_kernel(const int* __restrict__ perm,
    const float* __restrict__ gval, const float* __restrict__ x,
    float* __restrict__ out) {
  int i = blockIdx.x * 256 + threadIdx.x;
  int r = i >> 4, c = i & 15;
  int node = perm[r];
  float v = gval[r];
  float4 xv = reinterpret_cast<const float4*>(x)[(size_t)node * 16 + c];
  float4 o; o.x = xv.x * v; o.y = xv.y * v; o.z = xv.z * v; o.w = xv.w * v;
  reinterpret_cast<float4*>(out)[(size_t)r * 16 + c] = o;
}

extern "C" void kernel_launch(void* const* d_in, const int* in_sizes, int n_in,
                              void* d_out, int out_size, void* d_ws, size_t ws_size,
                              hipStream_t stream) {
  const int N = in_sizes[0] / 3;
  const int E = in_sizes[1] / 2;

  const float* pos   = (const float*)d_in[0];
  const int*   ei    = (const int*)d_in[1];
  const int*   src   = ei;
  const int*   dst   = ei + E;
  const float* c1_lw = (const float*)d_in[2];
  const float* c1_lb = (const float*)d_in[3];
  const float* c1_w1 = (const float*)d_in[4];
  const float* c1_b1 = (const float*)d_in[5];
  const float* c1_g1 = (const float*)d_in[6];
  const float* c1_be1= (const float*)d_in[7];
  const float* c1_w2 = (const float*)d_in[8];
  const float* c1_b2 = (const float*)d_in[9];
  const float* c2_lw = (const float*)d_in[10];
  const float* c2_lb = (const float*)d_in[11];
  const float* c2_w1 = (const float*)d_in[12];
  const float* c2_b1 = (const float*)d_in[13];
  const float* c2_g1 = (const float*)d_in[14];
  const float* c2_be1= (const float*)d_in[15];
  const float* c2_w2 = (const float*)d_in[16];
  const float* c2_b2 = (const float*)d_in[17];
  const float* poolw = (const float*)d_in[18];

  // ---- workspace layout ----
  float* ws = (float*)d_ws;
  float* x1   = ws;                         // 16N
  float* h1   = ws + (size_t)16 * N;        // 32N
  float* o1   = ws + (size_t)48 * N;        // 16N
  float* res2 = ws;                         // 64N
  float* x2   = ws + (size_t)64 * N;        // 64N
  float* res1 = x2;                         // 16N
  float* h2   = ws + (size_t)128 * N;       // 128N
  float* o2   = ws + (size_t)256 * N;       // 64N
  float* scores = ws + (size_t)320 * N;     // N
  u64* candA = (u64*)(ws + (size_t)321 * N);            // N
  u64* candB = candA + N;                               // N
  u64* sel   = candB + N;                               // 512
  double* partial = (double*)(sel + TOPK);              // 4 MB reserved
  int* ibase   = (int*)(partial + (size_t)524288);
  int* istate  = ibase;            // 8
  int* hist    = ibase + 8;        // 256
  int* perm    = ibase + 776;      // 512
  float* gval  = (float*)(ibase + 1288);    // 512
  int* deg     = ibase + 1800;     // N
  int* rowstart= deg + N;          // N
  int* eidx    = rowstart + N;     // E
  int* pairbuf = eidx + E;         // E
  int* pcnt    = pairbuf + E;      // PA*MAXBUK
  int* poff    = pcnt + PA * MAXBUK;  // PA*MAXBUK
  int* ptot    = poff + PA * MAXBUK;  // MAXBUK+1
  float* fsc   = (float*)(ptot + MAXBUK + 1);
  float* sc1 = fsc;        float* sh1 = fsc + 32;
  float* sc2 = fsc + 64;   float* sh2 = fsc + 192;     // 320 floats total

  const int nbN = (N + BLK - 1) / BLK;
  const int nbG = (N + 63) / 64;
  const int NBUK = (N + (1 << BSH) - 1) >> BSH;
  const int chunk = (E + PA - 1) / PA;

  // replay-safe zeroing: istate/hist are atomic accumulation targets
  hipMemsetAsync(ibase, 0, 1800 * sizeof(int), stream);

  // ---- CSR build (atomic-free: counting sort; deg/rowstart derived in LDS) ----
  pcount_kernel<<<PA, BLK, 0, stream>>>(dst, pcnt, E, chunk);
  pscan_kernel<<<1, 256, 0, stream>>>(pcnt, poff, ptot, PA, NBUK);
  ppack_kernel<<<PA, BLK, 0, stream>>>(src, dst, poff, ptot, pairbuf, E, chunk);
  place_kernel<<<NBUK, BLK, 0, stream>>>(pairbuf, ptot, deg, rowstart, eidx, N);

  // ---- conv1 ----
  lin_kernel<3, 16, 16><<<dim3(nbN, 1), BLK, 0, stream>>>(pos, c1_lw, c1_lb, x1, nullptr, N);
  agg_kernel<16><<<(N * 16 + BLK - 1) / BLK, BLK, 0, stream>>>(rowstart, deg, eidx, x1, res1, N);
  lin_kernel<16, 32, 32, true><<<dim3(nbN, 1), BLK, 0, stream>>>(res1, c1_w1, c1_b1, h1, partial, N);
  bn_fin3<32, 32><<<32, 256, 0, stream>>>(partial, c1_g1, c1_be1, sc1, sh1, N, nbN);
  mlp2_kernel<32, 16, 16><<<dim3(nbN, 1), BLK, 0, stream>>>(h1, sc1, sh1, c1_w2, c1_b2, o1, N);

  // ---- conv2 ----
  gemm_tile<16, 64, 4, false, false, false><<<nbG, 256, 0, stream>>>(
      o1, c2_lw, c2_lb, nullptr, nullptr, x2, nullptr, N);
  agg_kernel<64><<<(N * 64 + BLK - 1) / BLK, BLK, 0, stream>>>(rowstart, deg, eidx, x2, res2, N);
  gemm_tile<64, 128, 4, false, false, true><<<nbG, 256, 0, stream>>>(
      res2, c2_w1, c2_b1, nullptr, nullptr, h2, partial, N);
  bn_fin_ws<128><<<128, 256, 0, stream>>>(partial, c2_g1, c2_be1, sc2, sh2, N, nbG);
  gemm_tile<128, 64, 4, true, true, false><<<nbG, 256, 0, stream>>>(
      h2, c2_w2, c2_b2, sc2, sh2, o2, nullptr, N);

  // ---- scores + exact top-K ----
  score_kernel<<<nbN, BLK, 0, stream>>>(o2, poolw, scores, candA, hist, N);
  compact0_kernel<<<nbN, BLK, 0, stream>>>(candA, candB, sel, istate, hist, N);
  topk_finish<<<1, 1024, 0, stream>>>(candB, candA, sel, istate, scores, perm, gval);
  gather_kernel<<<32, 256, 0, stream>>>(perm, gval, o2, (float*)d_out);

  (void)n_in; (void)out_size; (void)ws_size;
}